// Round 6
// baseline (2203.178 us; speedup 1.0000x reference)
//
#include <hip/hip_runtime.h>

#define Bn  64
#define Ln  1024
#define Pn  64
#define Hn  256
#define THn 768
#define ONn 128

typedef __attribute__((ext_vector_type(8))) short short8;
typedef __attribute__((ext_vector_type(4))) float f32x4;
typedef __attribute__((ext_vector_type(4))) int   i32x4;

__device__ __forceinline__ unsigned short f2bf(float f) {
    unsigned u = __float_as_uint(f);
    unsigned r = (u + 0x7FFFu + ((u >> 16) & 1u)) >> 16;
    return (unsigned short)r;
}
__device__ __forceinline__ float bf2f(unsigned short s) {
    return __uint_as_float(((unsigned)s) << 16);
}
__device__ __forceinline__ float sigm(float x) { return 1.0f / (1.0f + __expf(-x)); }
// branch-free tanh via v_exp_f32; exact at saturation (exp->inf => 1, exp->0 => -1)
__device__ __forceinline__ float ftanh(float x) { return 1.0f - 2.0f / (__expf(2.0f * x) + 1.0f); }

__device__ __forceinline__ short8 pack8(const float* __restrict__ p) {
    const float4 f0 = *(const float4*)p;
    const float4 f1 = *(const float4*)(p + 4);
    short8 r;
    r[0] = (short)f2bf(f0.x); r[1] = (short)f2bf(f0.y);
    r[2] = (short)f2bf(f0.z); r[3] = (short)f2bf(f0.w);
    r[4] = (short)f2bf(f1.x); r[5] = (short)f2bf(f1.y);
    r[6] = (short)f2bf(f1.z); r[7] = (short)f2bf(f1.w);
    return r;
}

// ---------------------------------------------------------------------------
// K1: gi_e[b,t,col] = x[b,t,:] @ W_ih_e[col,:] + b_ih_e[col] (+ b_hh_e[col] for r,z)
// stored bf16. Grid 512, block 256 (4 waves). Wave w covers cols [192w,192w+192).
// ---------------------------------------------------------------------------
__global__ __launch_bounds__(256) void k1_gi(const float* __restrict__ x,
        const float* __restrict__ Wih, const float* __restrict__ bih,
        const float* __restrict__ bhh, unsigned short* __restrict__ gi) {
    const int tid = threadIdx.x;
    const int wv = tid >> 6;
    const int lane = tid & 63;
    const int l15 = lane & 15;
    const int grp = lane >> 4;
    const long row0 = (long)blockIdx.x * 128;

    short8 wf[12][2];
#pragma unroll
    for (int tn = 0; tn < 12; ++tn) {
        const int col = 192 * wv + 16 * tn + l15;
#pragma unroll
        for (int tk = 0; tk < 2; ++tk)
            wf[tn][tk] = pack8(Wih + (long)col * Pn + 32 * tk + 8 * grp);
    }
    float biasv[12];
#pragma unroll
    for (int tn = 0; tn < 12; ++tn) {
        const int col = 192 * wv + 16 * tn + l15;
        biasv[tn] = bih[col] + (col < 512 ? bhh[col] : 0.0f); // fold b_hh into r,z gates
    }

    for (int m = 0; m < 8; ++m) {
        const long arow = row0 + 16 * m + l15;
        short8 af[2];
#pragma unroll
        for (int tk = 0; tk < 2; ++tk)
            af[tk] = pack8(x + arow * Pn + 32 * tk + 8 * grp);
#pragma unroll
        for (int tn = 0; tn < 12; ++tn) {
            f32x4 z4 = {0.f, 0.f, 0.f, 0.f};
            f32x4 acc = __builtin_amdgcn_mfma_f32_16x16x32_bf16(af[0], wf[tn][0], z4, 0, 0, 0);
            acc = __builtin_amdgcn_mfma_f32_16x16x32_bf16(af[1], wf[tn][1], acc, 0, 0, 0);
#pragma unroll
            for (int r = 0; r < 4; ++r) {
                const long row = row0 + 16 * m + 4 * grp + r;
                gi[row * THn + 192 * wv + 16 * tn + l15] = f2bf(acc[r] + biasv[tn]);
            }
        }
    }
}

// ---------------------------------------------------------------------------
// K2/K4: persistent GRU recurrence, INT8 matvec (mfma_i32_16x16x64_i8).
// One WG (8 waves) per batch; wave w owns units [32w,32w+32).
// Schedule (this round): the step interleaves VALU with the MFMA-issue window:
//   prefetch gi[t+1] -> early gate-input converts -> RZ MFMAs (tn0-3, per-tk
//   ds_read interleave) -> DEFERRED global store of h(t-1) -> r,z sigmoid
//   chains (TRANS) -> N MFMAs (tn4,5) issue under those chains -> n gate ->
//   quantize+LDS publish -> lgkmcnt-only barrier.
// Quantization unchanged from the verified R5 kernel: per-column W scales
// (colmax/127), h x127 symmetric, exact i32 accumulate, hprev stays f32.
// ---------------------------------------------------------------------------
template<int DEC>
__global__ __launch_bounds__(512, 2) void k_rec(
    const float* __restrict__ Whh, const float* __restrict__ bhh,
    const unsigned short* __restrict__ gi_bf,   // encoder: (B,L,768) bf16
    const float* __restrict__ gi_c,             // decoder: (B,768) f32 (biases folded)
    const float* __restrict__ s0,               // dec: last_h (B,256) f32
    unsigned short* __restrict__ h_seq,         // enc out: (B,L,256) bf16
    float* __restrict__ s_seq,                  // dec out: (B,L,256) f32
    float* __restrict__ last_h)                 // enc out: (B,256) f32
{
    const int b = blockIdx.x;
    const int tid = threadIdx.x;
    const int wv = tid >> 6;          // 0..7
    const int lane = tid & 63;
    const int l15 = lane & 15;
    const int grp = lane >> 4;
    const int hb = 32 * wv;           // this wave's hidden-slice base

    __shared__ i32x4 hbuf4[2][16];    // int8 h state, 256 B per buffer, 16B aligned
    char* const hb8 = (char*)hbuf4;   // flat view: [par*256 + idx]

    // ---- quantize W_hh columns to i8 (once). tn = g*2+j, col per lane ----
    i32x4 wf[6][4];
    float swq[6];                     // sw[col]/127 = colmax/(127*127)
#pragma unroll
    for (int tn = 0; tn < 6; ++tn) {
        const int g = tn >> 1, j = tn & 1;
        const int col = 256 * g + hb + 16 * j + l15;
        const float* wp = Whh + (long)col * Hn + 16 * grp;
        float amax = 0.0f;
#pragma unroll
        for (int tk = 0; tk < 4; ++tk) {
            const float* p = wp + 64 * tk;
#pragma unroll
            for (int q = 0; q < 4; ++q) {
                const float4 f = ((const float4*)p)[q];
                amax = fmaxf(amax, fmaxf(fmaxf(fabsf(f.x), fabsf(f.y)),
                                         fmaxf(fabsf(f.z), fabsf(f.w))));
            }
        }
        amax = fmaxf(amax, __shfl_xor(amax, 16));   // reduce across the 4 groups
        amax = fmaxf(amax, __shfl_xor(amax, 32));
        amax = fmaxf(amax, 1e-20f);
        const float inv_sw = 127.0f / amax;
        swq[tn] = amax * (1.0f / (127.0f * 127.0f));
#pragma unroll
        for (int tk = 0; tk < 4; ++tk) {
            const float* p = wp + 64 * tk;
            i32x4 r;
#pragma unroll
            for (int q = 0; q < 4; ++q) {
                const float4 f = ((const float4*)p)[q];
                const int b0 = (int)rintf(f.x * inv_sw) & 255;
                const int b1 = (int)rintf(f.y * inv_sw) & 255;
                const int b2 = (int)rintf(f.z * inv_sw) & 255;
                const int b3 = (int)rintf(f.w * inv_sw) & 255;
                r[q] = b0 | (b1 << 8) | (b2 << 16) | (b3 << 24);
            }
            wf[tn][tk] = r;
        }
    }
    float bhh_n[2];
#pragma unroll
    for (int j = 0; j < 2; ++j) bhh_n[j] = bhh[512 + hb + 16 * j + l15];

    float hprev[2];
    unsigned short giA[6], giB[6];
    float gic[6];

    const unsigned short* gl = nullptr;   // enc gi prefetch cursor
    unsigned short* hsp = nullptr;        // enc h_seq store cursor (deferred by 1 step)
    float* ssp = nullptr;                 // dec s_seq store cursor (deferred by 1 step)

    if (!DEC) {
#pragma unroll
        for (int j = 0; j < 2; ++j) hprev[j] = 0.0f;
        if (tid < 128) ((int*)hbuf4)[tid] = 0;   // zero both parity buffers
        gl = gi_bf + (long)b * Ln * THn + hb + l15;
#pragma unroll
        for (int g = 0; g < 3; ++g)
#pragma unroll
            for (int j = 0; j < 2; ++j)
                giA[g * 2 + j] = gl[256 * g + 16 * j];
        hsp = h_seq + (long)b * Ln * Hn + hb + l15;
    } else {
#pragma unroll
        for (int j = 0; j < 2; ++j) hprev[j] = s0[b * Hn + hb + 16 * j + l15];
        if (tid < 256) hb8[tid] = (char)(int)rintf(s0[b * Hn + tid] * 127.0f);
        const float* gd = gi_c + (long)b * THn;
#pragma unroll
        for (int g = 0; g < 3; ++g)
#pragma unroll
            for (int j = 0; j < 2; ++j)
                gic[g * 2 + j] = gd[256 * g + hb + 16 * j + l15];
        ssp = s_seq + (long)b * Ln * Hn + hb + l15;
    }
    __syncthreads();

    auto step = [&](int t, unsigned short (&gU)[6], unsigned short (&gP)[6]) {
        const int par = t & 1;
        const int nxt = par ^ 1;
        // A. prefetch gi[t+1] (encoder only) — stays in flight across the barrier.
        //    Final step's prefetch reads past gi_e into the allocated h_seq region.
        if (!DEC) {
            gl += THn;
#pragma unroll
            for (int g = 0; g < 3; ++g)
#pragma unroll
                for (int j = 0; j < 2; ++j)
                    gP[g * 2 + j] = gl[256 * g + 16 * j];
        }
        // B. early gate-input converts (independent of MFMAs; fills issue slots)
        float gir[2], giz[2], gin[2];
#pragma unroll
        for (int j = 0; j < 2; ++j) {
            gir[j] = DEC ? gic[j]     : bf2f(gU[j]);
            giz[j] = DEC ? gic[2 + j] : bf2f(gU[2 + j]);
            gin[j] = DEC ? gic[4 + j] : bf2f(gU[4 + j]);
        }
        // C. RZ MFMAs (tn 0..3): per-tk ds_read/MFMA interleave (proven schedule)
        i32x4 af[4];
        i32x4 acc[6];
#pragma unroll
        for (int tk = 0; tk < 4; ++tk) {
            af[tk] = *(const i32x4*)&hb8[par * 256 + 64 * tk + 16 * grp];
            if (tk == 0) {
                const i32x4 zi = {0, 0, 0, 0};
#pragma unroll
                for (int tn = 0; tn < 4; ++tn)
                    acc[tn] = __builtin_amdgcn_mfma_i32_16x16x64_i8(af[0], wf[tn][0], zi, 0, 0, 0);
            } else {
#pragma unroll
                for (int tn = 0; tn < 4; ++tn)
                    acc[tn] = __builtin_amdgcn_mfma_i32_16x16x64_i8(af[tk], wf[tn][tk], acc[tn], 0, 0, 0);
            }
        }
        // D. deferred global store of h(t-1) — issues inside the MFMA window,
        //    off the pre-barrier critical path. (hprev still holds h(t-1).)
        if (t != 0) {
            if (lane < 16) {
#pragma unroll
                for (int j = 0; j < 2; ++j) {
                    if (!DEC) hsp[16 * j] = f2bf(hprev[j]);
                    else      ssp[16 * j] = hprev[j];
                }
            }
            if (!DEC) hsp += Hn; else ssp += Hn;
        }
        // E. r,z gates — TRANS chains start while N MFMAs (F) issue below
        float rr[2], zz[2];
#pragma unroll
        for (int j = 0; j < 2; ++j) {
            const float ghr = (float)acc[j][0]     * swq[j];
            const float ghz = (float)acc[2 + j][0] * swq[2 + j];
            rr[j] = sigm(ghr + gir[j]);            // b_hh_r folded upstream
            zz[j] = sigm(ghz + giz[j]);            // b_hh_z folded upstream
        }
        // F. N MFMAs (tn 4,5) — af reused from registers
        {
            const i32x4 zi = {0, 0, 0, 0};
#pragma unroll
            for (int tn = 4; tn < 6; ++tn)
                acc[tn] = __builtin_amdgcn_mfma_i32_16x16x64_i8(af[0], wf[tn][0], zi, 0, 0, 0);
#pragma unroll
            for (int tk = 1; tk < 4; ++tk)
#pragma unroll
                for (int tn = 4; tn < 6; ++tn)
                    acc[tn] = __builtin_amdgcn_mfma_i32_16x16x64_i8(af[tk], wf[tn][tk], acc[tn], 0, 0, 0);
        }
        // G. n gate, combine, quantize + LDS publish (the only pre-barrier tail)
#pragma unroll
        for (int j = 0; j < 2; ++j) {
            const float ghn = (float)acc[4 + j][0] * swq[4 + j];
            const float n = ftanh(gin[j] + rr[j] * (ghn + bhh_n[j]));
            const float hnew = (1.0f - zz[j]) * n + zz[j] * hprev[j];
            hprev[j] = hnew;
            if (lane < 16)
                hb8[nxt * 256 + hb + 16 * j + l15] = (char)(int)rintf(hnew * 127.0f);
        }
        // H. barrier WITHOUT vmcnt drain (keep prefetch/deferred stores in flight)
        asm volatile("s_waitcnt lgkmcnt(0)\n\ts_barrier" ::: "memory");
    };

    for (int t = 0; t < Ln; t += 2) {
        step(t, giA, giB);
        step(t + 1, giB, giA);
    }

    // final deferred store: h(1023)/s(1023) at slot 1023 (cursor already there)
    if (lane < 16) {
#pragma unroll
        for (int j = 0; j < 2; ++j) {
            if (!DEC) {
                hsp[16 * j] = f2bf(hprev[j]);
                last_h[b * Hn + hb + 16 * j + l15] = hprev[j];
            } else {
                ssp[16 * j] = hprev[j];
            }
        }
    }
}

// ---------------------------------------------------------------------------
// K3: h_proj[l] = h_seq[b,l,:]·wa_h; alpha = softmax(h_proj); c = sum alpha*h;
// gi_d = c@Wihd^T + biases. h_proj phase: whole-wave dot per row (coalesced
// 512B row reads), 4 rows in flight per wave to hide shfl latency.
// ---------------------------------------------------------------------------
__global__ __launch_bounds__(256) void k3_ctx(const unsigned short* __restrict__ h_seq,
        const float* __restrict__ Wattn, const float* __restrict__ Wihd,
        const float* __restrict__ bihd, const float* __restrict__ bhhd,
        float* __restrict__ gi_d) {
    const int b = blockIdx.x;
    const int tid = threadIdx.x;
    const int wv = tid >> 6, lane = tid & 63;
    __shared__ float alpha[Ln];
    __shared__ float red[8];
    __shared__ float cbuf[Hn];
    __shared__ float wah[Hn];

    wah[tid] = Wattn[Hn + tid];   // wa_h = W_attn[0, H:2H]
    __syncthreads();

    const unsigned short* hb_ = h_seq + (long)b * Ln * Hn;
    const float4 wv4 = ((const float4*)wah)[lane];   // wa_h[4*lane .. 4*lane+3]

    // phase A: raw attention scores -> alpha[]
    for (int it = 0; it < 64; ++it) {
        const int lbase = it * 16 + wv * 4;          // 4 waves x 4 rows = 16 rows/iter
        const uint2 w0 = ((const uint2*)(hb_ + (long)(lbase + 0) * Hn))[lane];
        const uint2 w1 = ((const uint2*)(hb_ + (long)(lbase + 1) * Hn))[lane];
        const uint2 w2 = ((const uint2*)(hb_ + (long)(lbase + 2) * Hn))[lane];
        const uint2 w3 = ((const uint2*)(hb_ + (long)(lbase + 3) * Hn))[lane];
        float p0 = __uint_as_float(w0.x << 16) * wv4.x + __uint_as_float(w0.x & 0xffff0000u) * wv4.y
                 + __uint_as_float(w0.y << 16) * wv4.z + __uint_as_float(w0.y & 0xffff0000u) * wv4.w;
        float p1 = __uint_as_float(w1.x << 16) * wv4.x + __uint_as_float(w1.x & 0xffff0000u) * wv4.y
                 + __uint_as_float(w1.y << 16) * wv4.z + __uint_as_float(w1.y & 0xffff0000u) * wv4.w;
        float p2 = __uint_as_float(w2.x << 16) * wv4.x + __uint_as_float(w2.x & 0xffff0000u) * wv4.y
                 + __uint_as_float(w2.y << 16) * wv4.z + __uint_as_float(w2.y & 0xffff0000u) * wv4.w;
        float p3 = __uint_as_float(w3.x << 16) * wv4.x + __uint_as_float(w3.x & 0xffff0000u) * wv4.y
                 + __uint_as_float(w3.y << 16) * wv4.z + __uint_as_float(w3.y & 0xffff0000u) * wv4.w;
#pragma unroll
        for (int s = 1; s < 64; s <<= 1) {
            p0 += __shfl_xor(p0, s);
            p1 += __shfl_xor(p1, s);
            p2 += __shfl_xor(p2, s);
            p3 += __shfl_xor(p3, s);
        }
        if (lane == 0) {
            alpha[lbase + 0] = p0; alpha[lbase + 1] = p1;
            alpha[lbase + 2] = p2; alpha[lbase + 3] = p3;
        }
    }
    __syncthreads();

    // softmax over alpha[0..Ln)
    const float4 hp4 = ((const float4*)alpha)[tid];
    float m = fmaxf(fmaxf(hp4.x, hp4.y), fmaxf(hp4.z, hp4.w));
#pragma unroll
    for (int s = 1; s < 64; s <<= 1) m = fmaxf(m, __shfl_xor(m, s));
    if (lane == 0) red[wv] = m;
    __syncthreads();
    m = fmaxf(fmaxf(red[0], red[1]), fmaxf(red[2], red[3]));
    const float e0 = __expf(hp4.x - m), e1 = __expf(hp4.y - m);
    const float e2 = __expf(hp4.z - m), e3 = __expf(hp4.w - m);
    float ss = e0 + e1 + e2 + e3;
#pragma unroll
    for (int s = 1; s < 64; s <<= 1) ss += __shfl_xor(ss, s);
    if (lane == 0) red[4 + wv] = ss;
    __syncthreads();
    const float inv = 1.0f / (red[4] + red[5] + red[6] + red[7]);
    ((float4*)alpha)[tid] = make_float4(e0 * inv, e1 * inv, e2 * inv, e3 * inv);
    __syncthreads();

    // context accumulation (column-coalesced)
    float accv = 0.0f;
    const unsigned short* hs = hb_ + tid;
    for (int l = 0; l < Ln; ++l) accv += alpha[l] * bf2f(hs[(long)l * Hn]);
    cbuf[tid] = accv;
    __syncthreads();

    // gi_d = c @ Wihd^T + biases
    for (int c = wv; c < THn; c += 4) {
        const float4 wr = ((const float4*)(Wihd + (long)c * Hn))[lane];
        const float4 cc = ((const float4*)cbuf)[lane];
        float p = wr.x * cc.x + wr.y * cc.y + wr.z * cc.z + wr.w * cc.w;
#pragma unroll
        for (int s = 1; s < 64; s <<= 1) p += __shfl_xor(p, s);
        if (lane == 0)
            gi_d[(long)b * THn + c] = p + bihd[c] + (c < 512 ? bhhd[c] : 0.0f);
    }
}

// ---------------------------------------------------------------------------
// K5: y[l] = sigm(s_seq[b,l,:]·W_dec + b_dec); out[b,o] = y·W_out[o,:] + b_out[o]
// ---------------------------------------------------------------------------
__global__ __launch_bounds__(256) void k5_out(const float* __restrict__ s_seq,
        const float* __restrict__ Wdec, const float* __restrict__ bdec,
        const float* __restrict__ Wout, const float* __restrict__ bout,
        float* __restrict__ out) {
    const int b = blockIdx.x;
    const int tid = threadIdx.x, wv = tid >> 6, lane = tid & 63;
    __shared__ float yl[Ln];
    __shared__ float wd[Hn];
    wd[tid] = Wdec[tid];
    __syncthreads();

    const float* sb = s_seq + (long)b * Ln * Hn;
    const float4 wd4 = ((const float4*)wd)[lane];
    const float bd = bdec[0];

    for (int it = 0; it < 64; ++it) {
        const int lbase = it * 16 + wv * 4;
        const float4 v0 = ((const float4*)(sb + (long)(lbase + 0) * Hn))[lane];
        const float4 v1 = ((const float4*)(sb + (long)(lbase + 1) * Hn))[lane];
        const float4 v2 = ((const float4*)(sb + (long)(lbase + 2) * Hn))[lane];
        const float4 v3 = ((const float4*)(sb + (long)(lbase + 3) * Hn))[lane];
        float p0 = v0.x * wd4.x + v0.y * wd4.y + v0.z * wd4.z + v0.w * wd4.w;
        float p1 = v1.x * wd4.x + v1.y * wd4.y + v1.z * wd4.z + v1.w * wd4.w;
        float p2 = v2.x * wd4.x + v2.y * wd4.y + v2.z * wd4.z + v2.w * wd4.w;
        float p3 = v3.x * wd4.x + v3.y * wd4.y + v3.z * wd4.z + v3.w * wd4.w;
#pragma unroll
        for (int s = 1; s < 64; s <<= 1) {
            p0 += __shfl_xor(p0, s);
            p1 += __shfl_xor(p1, s);
            p2 += __shfl_xor(p2, s);
            p3 += __shfl_xor(p3, s);
        }
        if (lane == 0) {
            yl[lbase + 0] = sigm(p0 + bd); yl[lbase + 1] = sigm(p1 + bd);
            yl[lbase + 2] = sigm(p2 + bd); yl[lbase + 3] = sigm(p3 + bd);
        }
    }
    __syncthreads();

    for (int o = wv; o < ONn; o += 4) {
        const float* wr = Wout + (long)o * Ln;
        float p = 0.0f;
#pragma unroll
        for (int i = 0; i < 16; ++i) p += yl[lane + 64 * i] * wr[lane + 64 * i];
#pragma unroll
        for (int s = 1; s < 64; s <<= 1) p += __shfl_xor(p, s);
        if (lane == 0) out[b * ONn + o] = p + bout[o];
    }
}

// ---------------------------------------------------------------------------
extern "C" void kernel_launch(void* const* d_in, const int* in_sizes, int n_in,
                              void* d_out, int out_size, void* d_ws, size_t ws_size,
                              hipStream_t stream) {
    const float* x      = (const float*)d_in[0];
    const float* Wih_e  = (const float*)d_in[1];
    const float* Whh_e  = (const float*)d_in[2];
    const float* bih_e  = (const float*)d_in[3];
    const float* bhh_e  = (const float*)d_in[4];
    const float* Wih_d  = (const float*)d_in[5];
    const float* Whh_d  = (const float*)d_in[6];
    const float* bih_d  = (const float*)d_in[7];
    const float* bhh_d  = (const float*)d_in[8];
    const float* Wdec   = (const float*)d_in[9];
    const float* bdec   = (const float*)d_in[10];
    const float* Wattn  = (const float*)d_in[11];
    const float* Wout   = (const float*)d_in[13];
    const float* bout   = (const float*)d_in[14];
    float* out = (float*)d_out;

    char* ws = (char*)d_ws;
    unsigned short* gi_e  = (unsigned short*)ws;                    // [0, 100663296) 96 MB
    unsigned short* h_seq = (unsigned short*)(ws + 100663296);      // 32 MB
    float* last_h = (float*)(ws + 134217728);                       // 64 KB
    float* gi_d   = (float*)(ws + 134283264);                       // 192 KB
    float* s_seq  = (float*)ws;                                     // reuse gi_e (dead after enc), 64 MB

    k1_gi<<<512, 256, 0, stream>>>(x, Wih_e, bih_e, bhh_e, gi_e);
    k_rec<0><<<Bn, 512, 0, stream>>>(Whh_e, bhh_e, gi_e, nullptr, nullptr,
                                     h_seq, nullptr, last_h);
    k3_ctx<<<Bn, 256, 0, stream>>>(h_seq, Wattn, Wih_d, bih_d, bhh_d, gi_d);
    k_rec<1><<<Bn, 512, 0, stream>>>(Whh_d, bhh_d, nullptr, gi_d, last_h,
                                     nullptr, s_seq, nullptr);
    k5_out<<<Bn, 256, 0, stream>>>(s_seq, Wdec, bdec, Wout, bout, out);
}

// Round 7
// 1663.695 us; speedup vs baseline: 1.3243x; 1.3243x over previous
//
#include <hip/hip_runtime.h>

#define Bn  64
#define Ln  1024
#define Pn  64
#define Hn  256
#define THn 768
#define ONn 128

typedef __attribute__((ext_vector_type(8))) short short8;
typedef __attribute__((ext_vector_type(4))) float f32x4;
typedef __attribute__((ext_vector_type(4))) int   i32x4;

__device__ __forceinline__ unsigned short f2bf(float f) {
    unsigned u = __float_as_uint(f);
    unsigned r = (u + 0x7FFFu + ((u >> 16) & 1u)) >> 16;
    return (unsigned short)r;
}
__device__ __forceinline__ float bf2f(unsigned short s) {
    return __uint_as_float(((unsigned)s) << 16);
}
__device__ __forceinline__ float sigm(float x) { return 1.0f / (1.0f + __expf(-x)); }
// branch-free tanh via v_exp_f32; exact at saturation (exp->inf => 1, exp->0 => -1)
__device__ __forceinline__ float ftanh(float x) { return 1.0f - 2.0f / (__expf(2.0f * x) + 1.0f); }

__device__ __forceinline__ short8 pack8(const float* __restrict__ p) {
    const float4 f0 = *(const float4*)p;
    const float4 f1 = *(const float4*)(p + 4);
    short8 r;
    r[0] = (short)f2bf(f0.x); r[1] = (short)f2bf(f0.y);
    r[2] = (short)f2bf(f0.z); r[3] = (short)f2bf(f0.w);
    r[4] = (short)f2bf(f1.x); r[5] = (short)f2bf(f1.y);
    r[6] = (short)f2bf(f1.z); r[7] = (short)f2bf(f1.w);
    return r;
}

// ---------------------------------------------------------------------------
// K1: gi_e[b,t,col] = x[b,t,:] @ W_ih_e[col,:] + b_ih_e[col] (+ b_hh_e[col] for r,z)
// stored bf16. Grid 512, block 256 (4 waves). Wave w covers cols [192w,192w+192).
// ---------------------------------------------------------------------------
__global__ __launch_bounds__(256) void k1_gi(const float* __restrict__ x,
        const float* __restrict__ Wih, const float* __restrict__ bih,
        const float* __restrict__ bhh, unsigned short* __restrict__ gi) {
    const int tid = threadIdx.x;
    const int wv = tid >> 6;
    const int lane = tid & 63;
    const int l15 = lane & 15;
    const int grp = lane >> 4;
    const long row0 = (long)blockIdx.x * 128;

    short8 wf[12][2];
#pragma unroll
    for (int tn = 0; tn < 12; ++tn) {
        const int col = 192 * wv + 16 * tn + l15;
#pragma unroll
        for (int tk = 0; tk < 2; ++tk)
            wf[tn][tk] = pack8(Wih + (long)col * Pn + 32 * tk + 8 * grp);
    }
    float biasv[12];
#pragma unroll
    for (int tn = 0; tn < 12; ++tn) {
        const int col = 192 * wv + 16 * tn + l15;
        biasv[tn] = bih[col] + (col < 512 ? bhh[col] : 0.0f); // fold b_hh into r,z gates
    }

    for (int m = 0; m < 8; ++m) {
        const long arow = row0 + 16 * m + l15;
        short8 af[2];
#pragma unroll
        for (int tk = 0; tk < 2; ++tk)
            af[tk] = pack8(x + arow * Pn + 32 * tk + 8 * grp);
#pragma unroll
        for (int tn = 0; tn < 12; ++tn) {
            f32x4 z4 = {0.f, 0.f, 0.f, 0.f};
            f32x4 acc = __builtin_amdgcn_mfma_f32_16x16x32_bf16(af[0], wf[tn][0], z4, 0, 0, 0);
            acc = __builtin_amdgcn_mfma_f32_16x16x32_bf16(af[1], wf[tn][1], acc, 0, 0, 0);
#pragma unroll
            for (int r = 0; r < 4; ++r) {
                const long row = row0 + 16 * m + 4 * grp + r;
                gi[row * THn + 192 * wv + 16 * tn + l15] = f2bf(acc[r] + biasv[tn]);
            }
        }
    }
}

// ---------------------------------------------------------------------------
// K2/K4: persistent GRU recurrence, INT8 matvec (mfma_i32_16x16x64_i8).
// One WG (8 waves) per batch; wave w owns units [32w,32w+32).
// R5-proven step shape (single per-tk ds_read/MFMA interleave block; no
// splitting — R3/R6 proved hand-splitting regresses). This round's change:
// ONE-UNIT-PER-LANE gates. Lane parity jj=grp&1 selects which of the wave's
// two col-tiles the lane owns (unit = hb + 16*jj + l15); the gate math,
// gi loads (6->3), and quant/publish run once per unit instead of 4x.
// acc tile selection is an explicit ternary (v_cndmask) — no runtime array
// indexing (rule #20). Outputs bit-identical to R5.
// Quantization: per-column W scales (colmax/127), h x127 symmetric, exact
// i32 accumulate, hprev stays f32.
// ---------------------------------------------------------------------------
template<int DEC>
__global__ __launch_bounds__(512, 2) void k_rec(
    const float* __restrict__ Whh, const float* __restrict__ bhh,
    const unsigned short* __restrict__ gi_bf,   // encoder: (B,L,768) bf16
    const float* __restrict__ gi_c,             // decoder: (B,768) f32 (biases folded)
    const float* __restrict__ s0,               // dec: last_h (B,256) f32
    unsigned short* __restrict__ h_seq,         // enc out: (B,L,256) bf16
    float* __restrict__ s_seq,                  // dec out: (B,L,256) f32
    float* __restrict__ last_h)                 // enc out: (B,256) f32
{
    const int b = blockIdx.x;
    const int tid = threadIdx.x;
    const int wv = tid >> 6;          // 0..7
    const int lane = tid & 63;
    const int l15 = lane & 15;
    const int grp = lane >> 4;
    const int hb = 32 * wv;           // this wave's hidden-slice base
    const int jj = grp & 1;           // which col-tile this lane owns
    const int unit = hb + 16 * jj + l15;   // this lane's hidden unit

    __shared__ i32x4 hbuf4[2][16];    // int8 h state, 256 B per buffer, 16B aligned
    char* const hb8 = (char*)hbuf4;   // flat view: [par*256 + idx]

    // ---- quantize W_hh columns to i8 (once). tn = g*2+j, col per lane ----
    i32x4 wf[6][4];
    float swq[6];                     // sw[col]/127 = colmax/(127*127)
#pragma unroll
    for (int tn = 0; tn < 6; ++tn) {
        const int g = tn >> 1, j = tn & 1;
        const int col = 256 * g + hb + 16 * j + l15;
        const float* wp = Whh + (long)col * Hn + 16 * grp;
        float amax = 0.0f;
#pragma unroll
        for (int tk = 0; tk < 4; ++tk) {
            const float* p = wp + 64 * tk;
#pragma unroll
            for (int q = 0; q < 4; ++q) {
                const float4 f = ((const float4*)p)[q];
                amax = fmaxf(amax, fmaxf(fmaxf(fabsf(f.x), fabsf(f.y)),
                                         fmaxf(fabsf(f.z), fabsf(f.w))));
            }
        }
        amax = fmaxf(amax, __shfl_xor(amax, 16));   // reduce across the 4 groups
        amax = fmaxf(amax, __shfl_xor(amax, 32));
        amax = fmaxf(amax, 1e-20f);
        const float inv_sw = 127.0f / amax;
        swq[tn] = amax * (1.0f / (127.0f * 127.0f));
#pragma unroll
        for (int tk = 0; tk < 4; ++tk) {
            const float* p = wp + 64 * tk;
            i32x4 r;
#pragma unroll
            for (int q = 0; q < 4; ++q) {
                const float4 f = ((const float4*)p)[q];
                const int b0 = (int)rintf(f.x * inv_sw) & 255;
                const int b1 = (int)rintf(f.y * inv_sw) & 255;
                const int b2 = (int)rintf(f.z * inv_sw) & 255;
                const int b3 = (int)rintf(f.w * inv_sw) & 255;
                r[q] = b0 | (b1 << 8) | (b2 << 16) | (b3 << 24);
            }
            wf[tn][tk] = r;
        }
    }
    // per-lane selected scales / bias for the lane's own unit (static indices)
    const float swr = jj ? swq[1] : swq[0];
    const float swz = jj ? swq[3] : swq[2];
    const float swn = jj ? swq[5] : swq[4];
    const float bhn = bhh[512 + unit];

    float hprev;
    unsigned short giA[3], giB[3];
    float gic[3];

    const unsigned short* gl = nullptr;   // enc gi prefetch cursor (per-lane unit)
    unsigned short* hsp = nullptr;        // enc h_seq store cursor
    float* ssp = nullptr;                 // dec s_seq store cursor

    if (!DEC) {
        hprev = 0.0f;
        if (tid < 128) ((int*)hbuf4)[tid] = 0;   // zero both parity buffers
        gl = gi_bf + (long)b * Ln * THn + unit;
#pragma unroll
        for (int g = 0; g < 3; ++g) giA[g] = gl[256 * g];
        hsp = h_seq + (long)b * Ln * Hn + unit;
    } else {
        hprev = s0[b * Hn + unit];
        if (tid < 256) hb8[tid] = (char)(int)rintf(s0[b * Hn + tid] * 127.0f);
        const float* gd = gi_c + (long)b * THn;
#pragma unroll
        for (int g = 0; g < 3; ++g) gic[g] = gd[256 * g + unit];
        ssp = s_seq + (long)b * Ln * Hn + unit;
    }
    __syncthreads();

    auto step = [&](int t, unsigned short (&gU)[3], unsigned short (&gP)[3]) {
        const int par = t & 1;
        const int nxt = par ^ 1;
        // 1. prefetch gi[t+1] (encoder only) — stays in flight across the barrier.
        //    Final step's prefetch reads past gi_e into the allocated h_seq region.
        if (!DEC) {
            gl += THn;
#pragma unroll
            for (int g = 0; g < 3; ++g) gP[g] = gl[256 * g];
        }
        // 2. gh = h @ Whh^T : 24 i8 MFMAs/wave, per-tk ds_read/MFMA interleave
        //    (R5-proven schedule — single block, do not split)
        i32x4 acc[6];
#pragma unroll
        for (int tk = 0; tk < 4; ++tk) {
            const i32x4 af = *(const i32x4*)&hb8[par * 256 + 64 * tk + 16 * grp];
            if (tk == 0) {
                const i32x4 zi = {0, 0, 0, 0};
#pragma unroll
                for (int tn = 0; tn < 6; ++tn)
                    acc[tn] = __builtin_amdgcn_mfma_i32_16x16x64_i8(af, wf[tn][0], zi, 0, 0, 0);
            } else {
#pragma unroll
                for (int tn = 0; tn < 6; ++tn)
                    acc[tn] = __builtin_amdgcn_mfma_i32_16x16x64_i8(af, wf[tn][tk], acc[tn], 0, 0, 0);
            }
        }
        // 3. gates — ONCE per unit (lane's jj selects its tile via cndmask)
        const int ar = jj ? acc[1][0] : acc[0][0];
        const int az = jj ? acc[3][0] : acc[2][0];
        const int an = jj ? acc[5][0] : acc[4][0];
        const float gir = DEC ? gic[0] : bf2f(gU[0]);
        const float giz = DEC ? gic[1] : bf2f(gU[1]);
        const float gin = DEC ? gic[2] : bf2f(gU[2]);
        const float r = sigm((float)ar * swr + gir);    // b_hh_r folded upstream
        const float z = sigm((float)az * swz + giz);    // b_hh_z folded upstream
        const float n = ftanh(gin + r * ((float)an * swn + bhn));
        const float hnew = (1.0f - z) * n + z * hprev;
        hprev = hnew;
        // 4. publish h (i8, double-buffered) + state-sequence store (grp 0,1
        //    cover all 32 units of this wave; grps 2,3 are duplicates)
        if (grp < 2) {
            hb8[nxt * 256 + unit] = (char)(int)rintf(hnew * 127.0f);
            if (!DEC) hsp[0] = f2bf(hnew);
            else      ssp[0] = hnew;
        }
        if (!DEC) hsp += Hn; else ssp += Hn;
        // 5. barrier WITHOUT vmcnt drain (keep prefetch/stores in flight)
        asm volatile("s_waitcnt lgkmcnt(0)\n\ts_barrier" ::: "memory");
    };

    for (int t = 0; t < Ln; t += 2) {
        step(t, giA, giB);
        step(t + 1, giB, giA);
    }

    if (!DEC) {
        if (grp < 2) last_h[b * Hn + unit] = hprev;
    }
}

// ---------------------------------------------------------------------------
// K3: h_proj[l] = h_seq[b,l,:]·wa_h; alpha = softmax(h_proj); c = sum alpha*h;
// gi_d = c@Wihd^T + biases. h_proj phase: whole-wave dot per row (coalesced
// 512B row reads), 4 rows in flight per wave to hide shfl latency.
// ---------------------------------------------------------------------------
__global__ __launch_bounds__(256) void k3_ctx(const unsigned short* __restrict__ h_seq,
        const float* __restrict__ Wattn, const float* __restrict__ Wihd,
        const float* __restrict__ bihd, const float* __restrict__ bhhd,
        float* __restrict__ gi_d) {
    const int b = blockIdx.x;
    const int tid = threadIdx.x;
    const int wv = tid >> 6, lane = tid & 63;
    __shared__ float alpha[Ln];
    __shared__ float red[8];
    __shared__ float cbuf[Hn];
    __shared__ float wah[Hn];

    wah[tid] = Wattn[Hn + tid];   // wa_h = W_attn[0, H:2H]
    __syncthreads();

    const unsigned short* hb_ = h_seq + (long)b * Ln * Hn;
    const float4 wv4 = ((const float4*)wah)[lane];   // wa_h[4*lane .. 4*lane+3]

    // phase A: raw attention scores -> alpha[]
    for (int it = 0; it < 64; ++it) {
        const int lbase = it * 16 + wv * 4;          // 4 waves x 4 rows = 16 rows/iter
        const uint2 w0 = ((const uint2*)(hb_ + (long)(lbase + 0) * Hn))[lane];
        const uint2 w1 = ((const uint2*)(hb_ + (long)(lbase + 1) * Hn))[lane];
        const uint2 w2 = ((const uint2*)(hb_ + (long)(lbase + 2) * Hn))[lane];
        const uint2 w3 = ((const uint2*)(hb_ + (long)(lbase + 3) * Hn))[lane];
        float p0 = __uint_as_float(w0.x << 16) * wv4.x + __uint_as_float(w0.x & 0xffff0000u) * wv4.y
                 + __uint_as_float(w0.y << 16) * wv4.z + __uint_as_float(w0.y & 0xffff0000u) * wv4.w;
        float p1 = __uint_as_float(w1.x << 16) * wv4.x + __uint_as_float(w1.x & 0xffff0000u) * wv4.y
                 + __uint_as_float(w1.y << 16) * wv4.z + __uint_as_float(w1.y & 0xffff0000u) * wv4.w;
        float p2 = __uint_as_float(w2.x << 16) * wv4.x + __uint_as_float(w2.x & 0xffff0000u) * wv4.y
                 + __uint_as_float(w2.y << 16) * wv4.z + __uint_as_float(w2.y & 0xffff0000u) * wv4.w;
        float p3 = __uint_as_float(w3.x << 16) * wv4.x + __uint_as_float(w3.x & 0xffff0000u) * wv4.y
                 + __uint_as_float(w3.y << 16) * wv4.z + __uint_as_float(w3.y & 0xffff0000u) * wv4.w;
#pragma unroll
        for (int s = 1; s < 64; s <<= 1) {
            p0 += __shfl_xor(p0, s);
            p1 += __shfl_xor(p1, s);
            p2 += __shfl_xor(p2, s);
            p3 += __shfl_xor(p3, s);
        }
        if (lane == 0) {
            alpha[lbase + 0] = p0; alpha[lbase + 1] = p1;
            alpha[lbase + 2] = p2; alpha[lbase + 3] = p3;
        }
    }
    __syncthreads();

    // softmax over alpha[0..Ln)
    const float4 hp4 = ((const float4*)alpha)[tid];
    float m = fmaxf(fmaxf(hp4.x, hp4.y), fmaxf(hp4.z, hp4.w));
#pragma unroll
    for (int s = 1; s < 64; s <<= 1) m = fmaxf(m, __shfl_xor(m, s));
    if (lane == 0) red[wv] = m;
    __syncthreads();
    m = fmaxf(fmaxf(red[0], red[1]), fmaxf(red[2], red[3]));
    const float e0 = __expf(hp4.x - m), e1 = __expf(hp4.y - m);
    const float e2 = __expf(hp4.z - m), e3 = __expf(hp4.w - m);
    float ss = e0 + e1 + e2 + e3;
#pragma unroll
    for (int s = 1; s < 64; s <<= 1) ss += __shfl_xor(ss, s);
    if (lane == 0) red[4 + wv] = ss;
    __syncthreads();
    const float inv = 1.0f / (red[4] + red[5] + red[6] + red[7]);
    ((float4*)alpha)[tid] = make_float4(e0 * inv, e1 * inv, e2 * inv, e3 * inv);
    __syncthreads();

    // context accumulation (column-coalesced)
    float accv = 0.0f;
    const unsigned short* hs = hb_ + tid;
    for (int l = 0; l < Ln; ++l) accv += alpha[l] * bf2f(hs[(long)l * Hn]);
    cbuf[tid] = accv;
    __syncthreads();

    // gi_d = c @ Wihd^T + biases
    for (int c = wv; c < THn; c += 4) {
        const float4 wr = ((const float4*)(Wihd + (long)c * Hn))[lane];
        const float4 cc = ((const float4*)cbuf)[lane];
        float p = wr.x * cc.x + wr.y * cc.y + wr.z * cc.z + wr.w * cc.w;
#pragma unroll
        for (int s = 1; s < 64; s <<= 1) p += __shfl_xor(p, s);
        if (lane == 0)
            gi_d[(long)b * THn + c] = p + bihd[c] + (c < 512 ? bhhd[c] : 0.0f);
    }
}

// ---------------------------------------------------------------------------
// K5: y[l] = sigm(s_seq[b,l,:]·W_dec + b_dec); out[b,o] = y·W_out[o,:] + b_out[o]
// ---------------------------------------------------------------------------
__global__ __launch_bounds__(256) void k5_out(const float* __restrict__ s_seq,
        const float* __restrict__ Wdec, const float* __restrict__ bdec,
        const float* __restrict__ Wout, const float* __restrict__ bout,
        float* __restrict__ out) {
    const int b = blockIdx.x;
    const int tid = threadIdx.x, wv = tid >> 6, lane = tid & 63;
    __shared__ float yl[Ln];
    __shared__ float wd[Hn];
    wd[tid] = Wdec[tid];
    __syncthreads();

    const float* sb = s_seq + (long)b * Ln * Hn;
    const float4 wd4 = ((const float4*)wd)[lane];
    const float bd = bdec[0];

    for (int it = 0; it < 64; ++it) {
        const int lbase = it * 16 + wv * 4;
        const float4 v0 = ((const float4*)(sb + (long)(lbase + 0) * Hn))[lane];
        const float4 v1 = ((const float4*)(sb + (long)(lbase + 1) * Hn))[lane];
        const float4 v2 = ((const float4*)(sb + (long)(lbase + 2) * Hn))[lane];
        const float4 v3 = ((const float4*)(sb + (long)(lbase + 3) * Hn))[lane];
        float p0 = v0.x * wd4.x + v0.y * wd4.y + v0.z * wd4.z + v0.w * wd4.w;
        float p1 = v1.x * wd4.x + v1.y * wd4.y + v1.z * wd4.z + v1.w * wd4.w;
        float p2 = v2.x * wd4.x + v2.y * wd4.y + v2.z * wd4.z + v2.w * wd4.w;
        float p3 = v3.x * wd4.x + v3.y * wd4.y + v3.z * wd4.z + v3.w * wd4.w;
#pragma unroll
        for (int s = 1; s < 64; s <<= 1) {
            p0 += __shfl_xor(p0, s);
            p1 += __shfl_xor(p1, s);
            p2 += __shfl_xor(p2, s);
            p3 += __shfl_xor(p3, s);
        }
        if (lane == 0) {
            yl[lbase + 0] = sigm(p0 + bd); yl[lbase + 1] = sigm(p1 + bd);
            yl[lbase + 2] = sigm(p2 + bd); yl[lbase + 3] = sigm(p3 + bd);
        }
    }
    __syncthreads();

    for (int o = wv; o < ONn; o += 4) {
        const float* wr = Wout + (long)o * Ln;
        float p = 0.0f;
#pragma unroll
        for (int i = 0; i < 16; ++i) p += yl[lane + 64 * i] * wr[lane + 64 * i];
#pragma unroll
        for (int s = 1; s < 64; s <<= 1) p += __shfl_xor(p, s);
        if (lane == 0) out[b * ONn + o] = p + bout[o];
    }
}

// ---------------------------------------------------------------------------
extern "C" void kernel_launch(void* const* d_in, const int* in_sizes, int n_in,
                              void* d_out, int out_size, void* d_ws, size_t ws_size,
                              hipStream_t stream) {
    const float* x      = (const float*)d_in[0];
    const float* Wih_e  = (const float*)d_in[1];
    const float* Whh_e  = (const float*)d_in[2];
    const float* bih_e  = (const float*)d_in[3];
    const float* bhh_e  = (const float*)d_in[4];
    const float* Wih_d  = (const float*)d_in[5];
    const float* Whh_d  = (const float*)d_in[6];
    const float* bih_d  = (const float*)d_in[7];
    const float* bhh_d  = (const float*)d_in[8];
    const float* Wdec   = (const float*)d_in[9];
    const float* bdec   = (const float*)d_in[10];
    const float* Wattn  = (const float*)d_in[11];
    const float* Wout   = (const float*)d_in[13];
    const float* bout   = (const float*)d_in[14];
    float* out = (float*)d_out;

    char* ws = (char*)d_ws;
    unsigned short* gi_e  = (unsigned short*)ws;                    // [0, 100663296) 96 MB
    unsigned short* h_seq = (unsigned short*)(ws + 100663296);      // 32 MB
    float* last_h = (float*)(ws + 134217728);                       // 64 KB
    float* gi_d   = (float*)(ws + 134283264);                       // 192 KB
    float* s_seq  = (float*)ws;                                     // reuse gi_e (dead after enc), 64 MB

    k1_gi<<<512, 256, 0, stream>>>(x, Wih_e, bih_e, bhh_e, gi_e);
    k_rec<0><<<Bn, 512, 0, stream>>>(Whh_e, bhh_e, gi_e, nullptr, nullptr,
                                     h_seq, nullptr, last_h);
    k3_ctx<<<Bn, 256, 0, stream>>>(h_seq, Wattn, Wih_d, bih_d, bhh_d, gi_d);
    k_rec<1><<<Bn, 512, 0, stream>>>(Whh_d, bhh_d, nullptr, gi_d, last_h,
                                     nullptr, s_seq, nullptr);
    k5_out<<<Bn, 256, 0, stream>>>(s_seq, Wdec, bdec, Wout, bout, out);
}